// Round 1
// baseline (155.688 us; speedup 1.0000x reference)
//
#include <hip/hip_runtime.h>
#include <math.h>

// MoE top-2-of-8: B=1024, I=512, H=2048, O=512, E=8, K=2.
// R9: launch-count compaction. scatter_kernel deleted -- each fc1 block
// rebuilds its expert's slot list with a wave-0 ballot-scan over tok_e
// (deterministic token-order ranks, capacity-based slots e*1024+pos);
// fc1 block x==0 publishes counts/tok_slot for fc2/combine. fc2 goes
// kc=2 (BN=32, grid 16x2x8 = 256 blocks, full 1024-k panel resident in
// 66 KB LDS) -> y-partial round-trip halves to 16 MB. 4 kernels total:
// gating, fc1(+scan), fc2, combine. GEMM core is unchanged R8: contiguous
// 256B W row-segments transposed into LDS [n][k] bf16 via k-pair-packed
// ds_write_b32, per-lane direct global b128 A-frags, 16x16x32 bf16 MFMA.

#define B_TOK 1024
#define I_DIM 512
#define H_DIM 2048
#define O_DIM 512
#define E_NUM 8
#define CAP   1024                       // per-expert slot capacity (max Me)

#define WS_COUNTS   0                    // 8 ints   (written by fc1 x==0)
#define WS_TOK_E    64                   // [1024][2] int
#define WS_TOK_W    8256                 // [1024][2] float
#define WS_TOK_SLOT 16448                // [1024][2] int (written by fc1 x==0)
#define WS_XB       65536                // [1024][512] bf16 = 1 MB
#define WS_HB       (WS_XB + 1048576)    // [8*1024][2048] bf16 = 32 MB
#define WS_Y2       (WS_HB + 33554432)   // [2][8192][512] f32 = 32 MB

typedef __attribute__((ext_vector_type(8))) __bf16 bf16x8;
typedef __attribute__((ext_vector_type(4))) __bf16 bf16x4;
typedef __attribute__((ext_vector_type(2))) __bf16 bf16x2;
typedef __attribute__((ext_vector_type(4))) float f32x4;

#define MFMA16 __builtin_amdgcn_mfma_f32_16x16x32_bf16

// ---------------------------------------------------------------------------
// Gating: one wave per token. Also converts the token's x row to bf16 (xb).
__global__ __launch_bounds__(256) void gating_kernel(
    const float* __restrict__ x, const float* __restrict__ Wg,
    const float* __restrict__ bg, __bf16* __restrict__ xb,
    int* __restrict__ tok_e, float* __restrict__ tok_w)
{
    const int lane = threadIdx.x & 63;
    const int t = blockIdx.x * 4 + (threadIdx.x >> 6);
    const float4* x4 = (const float4*)(x + (size_t)t * I_DIM);
    float4 va = x4[lane], vb = x4[lane + 64];
    bf16x4 oa, ob;
    oa[0] = (__bf16)va.x; oa[1] = (__bf16)va.y;
    oa[2] = (__bf16)va.z; oa[3] = (__bf16)va.w;
    ob[0] = (__bf16)vb.x; ob[1] = (__bf16)vb.y;
    ob[2] = (__bf16)vb.z; ob[3] = (__bf16)vb.w;
    *(bf16x4*)(xb + (size_t)t * I_DIM + lane * 4) = oa;
    *(bf16x4*)(xb + (size_t)t * I_DIM + 256 + lane * 4) = ob;

    float acc[8];
#pragma unroll
    for (int e = 0; e < 8; ++e) acc[e] = 0.f;
    float xv[8] = {va.x, va.y, va.z, va.w, vb.x, vb.y, vb.z, vb.w};
#pragma unroll
    for (int u = 0; u < 8; ++u) {
        int i = (u < 4) ? (lane * 4 + u) : (256 + lane * 4 + u - 4);
        const float4* wr = (const float4*)(Wg + (size_t)i * 8);
        float4 wa = wr[0], wb2 = wr[1];
        acc[0] = fmaf(xv[u], wa.x, acc[0]);
        acc[1] = fmaf(xv[u], wa.y, acc[1]);
        acc[2] = fmaf(xv[u], wa.z, acc[2]);
        acc[3] = fmaf(xv[u], wa.w, acc[3]);
        acc[4] = fmaf(xv[u], wb2.x, acc[4]);
        acc[5] = fmaf(xv[u], wb2.y, acc[5]);
        acc[6] = fmaf(xv[u], wb2.z, acc[6]);
        acc[7] = fmaf(xv[u], wb2.w, acc[7]);
    }
#pragma unroll
    for (int off = 32; off > 0; off >>= 1)
#pragma unroll
        for (int e = 0; e < 8; ++e)
            acc[e] += __shfl_xor(acc[e], off, 64);
    if (lane == 0) {
        float l[8];
#pragma unroll
        for (int e = 0; e < 8; ++e) l[e] = acc[e] + bg[e];
        int e0 = 0;
        for (int e = 1; e < 8; ++e) if (l[e] > l[e0]) e0 = e;
        int e1 = (e0 == 0) ? 1 : 0;
        for (int e = 0; e < 8; ++e) {
            if (e == e0) continue;
            if (l[e] > l[e1]) e1 = e;
        }
        float w0 = 1.f / (1.f + expf(l[e1] - l[e0]));  // p0/(p0+p1)
        tok_e[t * 2]     = e0;
        tok_e[t * 2 + 1] = e1;
        tok_w[t * 2]     = w0;
        tok_w[t * 2 + 1] = 1.f - w0;
    }
}

// ---------------------------------------------------------------------------
// Weight-stationary GEMM, contiguous-W staging. 512 thr = 8 waves.
// IS_FC1:  BN=64, KSPAN=512. A=xb gathered via LDS slot list built by a
//          wave-0 ballot-scan of tok_e. Out=hb rows e*CAP+m (+bias,relu).
// !IS_FC1: BN=32, KSPAN=1024 (kc in {0,1}). A=hb rows e*CAP+m, Out=y2
//          f32 partials. Full K panel resident in LDS (overflow tiles ok).
template <bool IS_FC1>
__global__ __launch_bounds__(512) void moe_gemm(
    const __bf16* __restrict__ A, const float* __restrict__ Wf,
    const float* __restrict__ bias,
    int* __restrict__ counts, const int* __restrict__ tok_e,
    int* __restrict__ tok_slot,
    __bf16* __restrict__ hb, float* __restrict__ y2)
{
    constexpr int BN    = IS_FC1 ? 64 : 32;
    constexpr int KSPAN = IS_FC1 ? 512 : 1024;
    constexpr int BSTR  = KSPAN + 8;       // +8 pad: conflict-free reads (R7)
    constexpr int NCH   = KSPAN / 256;     // staged 256-k chunks
    constexpr int JN    = BN / 16;         // 16-col MFMA tiles per block
    constexpr int C4N   = BN / 4;          // col-quads per k-row-pair
    constexpr int NW    = IS_FC1 ? H_DIM : O_DIM;   // W col count (row stride)
    constexpr int ASTR  = IS_FC1 ? I_DIM : H_DIM;   // A row stride

    const int e  = blockIdx.z;
    const int kc = IS_FC1 ? 0 : (int)blockIdx.y;
    const int k0 = kc * KSPAN;
    const int n0 = blockIdx.x * BN;
    const int off = e * CAP;
    const float* W = Wf + (size_t)e * (IS_FC1 ? I_DIM * H_DIM : H_DIM * O_DIM);

    __shared__ __align__(16) __bf16 Bs[BN * BSTR];  // ~66 KB both paths
    __shared__ int sl_tok[IS_FC1 ? CAP : 1];
    __shared__ int sMe;

    const int tid = threadIdx.x;
    const int lane = tid & 63, w = tid >> 6;
    const int l15 = lane & 15, q = lane >> 4;

    // ---- fc1: wave-0 ballot-scan builds this expert's slot list in LDS ----
    // pos = rank of (t,k) among expert-e entries in token order: identical
    // across all 32 blocks of this expert (deterministic). Block x==0 also
    // publishes counts[e] and tok_slot for fc2/combine.
    if (IS_FC1 && w == 0) {
        int cnt = 0;
#pragma unroll
        for (int b = 0; b < 2; ++b) {
            int vals[16];
#pragma unroll
            for (int c = 0; c < 16; ++c)
                vals[c] = tok_e[(b * 16 + c) * 64 + lane];
#pragma unroll
            for (int c = 0; c < 16; ++c) {
                const int gidx = (b * 16 + c) * 64 + lane;
                const bool hit = (vals[c] == e);
                const unsigned long long mk = __ballot(hit);
                if (hit) {
                    const int pos = cnt + __popcll(mk & ((1ull << lane) - 1));
                    sl_tok[pos] = gidx >> 1;
                    if (blockIdx.x == 0) tok_slot[gidx] = off + pos;
                }
                cnt += __popcll(mk);
            }
        }
        if (lane == 0) {
            sMe = cnt;
            if (blockIdx.x == 0) counts[e] = cnt;
        }
    }
    const int MeG = IS_FC1 ? 0 : counts[e];

    // ---- contiguous staging of one 256-k chunk, transposed into Bs ----
    // unit u: k-row-pair p, col-quad c4. global: two contiguous float4 at
    // rows (2p, 2p+1); LDS: 4 k-pair-packed b32 writes.
    auto stage_chunk = [&](int ch) {
        const int kb = k0 + ch * 256;
#pragma unroll
        for (int i = 0; i < (128 * C4N) / 512; ++i) {
            const int u = tid + 512 * i;
            const int p = u / C4N, c4 = u % C4N;
            const float* wp = W + (size_t)(kb + 2 * p) * NW + n0 + c4 * 4;
            float4 r0 = *(const float4*)wp;
            float4 r1 = *(const float4*)(wp + NW);
            const float* f0 = (const float*)&r0;
            const float* f1 = (const float*)&r1;
#pragma unroll
            for (int j = 0; j < 4; ++j) {
                bf16x2 pk;
                pk[0] = (__bf16)f0[j];
                pk[1] = (__bf16)f1[j];
                *(bf16x2*)&Bs[(size_t)(c4 * 4 + j) * BSTR + ch * 256 + 2 * p] = pk;
            }
        }
    };

    stage_chunk(0);
    __syncthreads();                       // chunk 0 + slot list + sMe ready
#pragma unroll
    for (int ch = 1; ch < NCH; ++ch) stage_chunk(ch);   // overlap with compute

    const int Me = IS_FC1 ? sMe : MeG;

    auto set_aptr = [&](int m0, const __bf16*& a0, const __bf16*& a1) {
        int mA = m0 + l15;      if (mA >= Me) mA = Me - 1;
        int mB = m0 + 16 + l15; if (mB >= Me) mB = Me - 1;
        if (IS_FC1) {
            a0 = A + (size_t)sl_tok[mA] * ASTR + q * 8;
            a1 = A + (size_t)sl_tok[mB] * ASTR + q * 8;
        } else {
            a0 = A + (size_t)(off + mA) * ASTR + k0 + q * 8;
            a1 = A + (size_t)(off + mB) * ASTR + k0 + q * 8;
        }
    };
    auto compute = [&](const __bf16* a0, const __bf16* a1,
                       f32x4 (&acc)[2][JN], int ks0, int ks1) {
#pragma unroll 4
        for (int ks = ks0; ks < ks1; ++ks) {
            bf16x8 af0 = *(const bf16x8*)(a0 + ks * 32);
            bf16x8 af1 = *(const bf16x8*)(a1 + ks * 32);
#pragma unroll
            for (int jj = 0; jj < JN; ++jj) {
                bf16x8 bf = *(const bf16x8*)
                    &Bs[(size_t)(jj * 16 + l15) * BSTR + ks * 32 + q * 8];
                acc[0][jj] = MFMA16(af0, bf, acc[0][jj], 0, 0, 0);
                acc[1][jj] = MFMA16(af1, bf, acc[1][jj], 0, 0, 0);
            }
        }
    };
    // epilogue: C/D layout col=l15, row=q*4+reg (verified m89)
    auto epilogue = [&](int m0, f32x4 (&acc)[2][JN]) {
#pragma unroll
        for (int jj = 0; jj < JN; ++jj) {
            const int gn = n0 + jj * 16 + l15;
            if (IS_FC1) {
                const float bv = bias[e * H_DIM + gn];
#pragma unroll
                for (int i = 0; i < 2; ++i)
#pragma unroll
                    for (int r = 0; r < 4; ++r) {
                        int m = m0 + i * 16 + q * 4 + r;
                        if (m < Me) {
                            float v = acc[i][jj][r] + bv;
                            hb[(size_t)(off + m) * H_DIM + gn] =
                                (__bf16)fmaxf(v, 0.f);
                        }
                    }
            } else {
#pragma unroll
                for (int i = 0; i < 2; ++i)
#pragma unroll
                    for (int r = 0; r < 4; ++r) {
                        int m = m0 + i * 16 + q * 4 + r;
                        if (m < Me)
                            y2[((size_t)kc * (E_NUM * CAP) + off + m) * O_DIM + gn] =
                                acc[i][jj][r];
                    }
            }
        }
    };

    const bool act0 = (w * 32 < Me);
    int m0 = w * 32;
    f32x4 acc[2][JN] = {};
    const __bf16 *a0 = nullptr, *a1 = nullptr;
    if (act0) {
        set_aptr(m0, a0, a1);
        compute(a0, a1, acc, 0, 8);        // chunk-0 compute overlaps staging
    }
    __syncthreads();                       // chunks 1..NCH-1 resident
    if (act0) {
        compute(a0, a1, acc, 8, KSPAN / 32);
        epilogue(m0, acc);
    }
    for (m0 = w * 32 + 256; m0 < Me; m0 += 256) {   // overflow tiles (Me>256)
        f32x4 acc2[2][JN] = {};
        set_aptr(m0, a0, a1);
        compute(a0, a1, acc2, 0, KSPAN / 32);
        epilogue(m0, acc2);
    }
}

// out[t][c] = sum_k w_k * (b2[e_k][c] + sum_kc y2[kc][slot_k][c])
__global__ __launch_bounds__(256) void combine_kernel(
    const float* __restrict__ y2, const float* __restrict__ b2,
    const int* __restrict__ tok_slot, const int* __restrict__ tok_e,
    const float* __restrict__ tok_w, float* __restrict__ out)
{
    const int idx = blockIdx.x * 256 + threadIdx.x;   // B*O/4
    const int t = idx >> 7;
    const int c = (idx & 127) * 4;
    float4 sum = {0.f, 0.f, 0.f, 0.f};
#pragma unroll
    for (int k = 0; k < 2; ++k) {
        const int s = tok_slot[t * 2 + k];
        const int e = tok_e[t * 2 + k];
        const float wgt = tok_w[t * 2 + k];
        float4 a = *(const float4*)(b2 + (size_t)e * O_DIM + c);
#pragma unroll
        for (int kc = 0; kc < 2; ++kc) {
            float4 v = *(const float4*)
                (y2 + ((size_t)kc * (E_NUM * CAP) + s) * O_DIM + c);
            a.x += v.x; a.y += v.y; a.z += v.z; a.w += v.w;
        }
        sum.x += wgt * a.x; sum.y += wgt * a.y;
        sum.z += wgt * a.z; sum.w += wgt * a.w;
    }
    *(float4*)(out + (size_t)t * O_DIM + c) = sum;
}

extern "C" void kernel_launch(void* const* d_in, const int* in_sizes, int n_in,
                              void* d_out, int out_size, void* d_ws, size_t ws_size,
                              hipStream_t stream)
{
    const float* x  = (const float*)d_in[0];
    const float* Wg = (const float*)d_in[1];
    const float* bg = (const float*)d_in[2];
    const float* W1 = (const float*)d_in[3];
    const float* b1 = (const float*)d_in[4];
    const float* W2 = (const float*)d_in[5];
    const float* b2 = (const float*)d_in[6];
    float* out = (float*)d_out;
    char* ws = (char*)d_ws;

    int*    counts   = (int*)(ws + WS_COUNTS);
    int*    tok_e    = (int*)(ws + WS_TOK_E);
    float*  tok_w    = (float*)(ws + WS_TOK_W);
    int*    tok_slot = (int*)(ws + WS_TOK_SLOT);
    __bf16* xb       = (__bf16*)(ws + WS_XB);
    __bf16* hb       = (__bf16*)(ws + WS_HB);
    float*  y2       = (float*)(ws + WS_Y2);

    gating_kernel<<<B_TOK / 4, 256, 0, stream>>>(x, Wg, bg, xb, tok_e, tok_w);
    // fc1: 32 n-panels x 8 experts = 256 blocks (1/CU, whole chip)
    moe_gemm<true><<<dim3(32, 1, 8), 512, 0, stream>>>(
        xb, W1, b1, counts, tok_e, tok_slot, hb, y2);
    // fc2: 16 n-panels x 2 k-chunks x 8 experts = 256 blocks
    moe_gemm<false><<<dim3(16, 2, 8), 512, 0, stream>>>(
        hb, W2, b2, counts, tok_e, tok_slot, hb, y2);
    combine_kernel<<<(B_TOK * O_DIM / 4) / 256, 256, 0, stream>>>(
        y2, b2, tok_slot, tok_e, tok_w, out);
}